// Round 26
// baseline (43.881 us; speedup 1.0000x reference)
//
#include <hip/hip_runtime.h>
#include <math.h>

#define D_DIM   128
#define MAXNORM 0.99f
#define MN2     (0.99f * 0.99f)

typedef float f32x4 __attribute__((ext_vector_type(4)));

// DPP-based reductions: VALU pipe only (r18-verified).
template <int CTRL, int MASK>
__device__ __forceinline__ float dpp_add(float x) {
  int y = __builtin_amdgcn_update_dpp(0, __float_as_int(x), CTRL, MASK, 0xf, true);
  return x + __int_as_float(y);
}
__device__ __forceinline__ float dpp_sum64(float x) {
  x = dpp_add<0x111, 0xf>(x);   // row_shr:1
  x = dpp_add<0x112, 0xf>(x);   // row_shr:2
  x = dpp_add<0x114, 0xf>(x);   // row_shr:4
  x = dpp_add<0x118, 0xf>(x);   // row_shr:8
  x = dpp_add<0x142, 0xa>(x);   // row_bcast15
  x = dpp_add<0x143, 0xc>(x);   // row_bcast31
  return __int_as_float(__builtin_amdgcn_readlane(__float_as_int(x), 63));
}
__device__ __forceinline__ float dpp_sum32(float x) {
  x = dpp_add<0x111, 0xf>(x);
  x = dpp_add<0x112, 0xf>(x);
  x = dpp_add<0x114, 0xf>(x);
  x = dpp_add<0x118, 0xf>(x);
  x = dpp_add<0x142, 0xa>(x);
  return x;
}

// ONE sample per 128-thread block (2 waves): barriers couple only the 2 waves
// that share data (r25's 256-thread block falsely coupled 2 independent
// samples at every barrier). Grid 4096 -> 16 blocks/CU = 32 waves/CU.
// launch_bounds(128,8): 8 waves/SIMD -> VGPR cap 64 (r25-verified regime).
__global__ __launch_bounds__(128, 8) void k_all(
    const float* __restrict__ z_n, const float* __restrict__ centers,
    const float* __restrict__ rot, const int* __restrict__ src_idx,
    const int* __restrict__ tgt_idx, float* __restrict__ out, int B)
{
  __shared__ float zbuf[D_DIM];      // z_global
  __shared__ float vbuf[D_DIM];      // v = Rt @ zg
  __shared__ float pbuf[2][D_DIM];   // stage-B partials per wave

  const int tid = threadIdx.x;
  const int p = tid >> 6, l = tid & 63;   // wave-in-pair, lane
  const int h = l >> 5, q = l & 31;
  const int b = blockIdx.x;
  if (b >= B) return;

  const int ct = tgt_idx[b];
  const int cs = src_idx[b];

  // ---- Mobius A (replicated in the pair; p==0 publishes). Lane owns comps 2l,2l+1.
  float2 z = ((const float2*)(z_n + (size_t)b * D_DIM))[l];
  float2 c = ((const float2*)(centers + (size_t)cs * D_DIM))[l];
  {
    float y2p = dpp_sum64(z.x * z.x + z.y * z.y);
    float x2p = dpp_sum64(c.x * c.x + c.y * c.y);
    float cz  = dpp_sum64(c.x * z.x + c.y * z.y);
    float sz = 1.0f, y2 = y2p;
    if (y2p > MN2) { sz = MAXNORM / sqrtf(y2p); y2 = MN2; }
    float sc = 1.0f, x2 = x2p;
    if (x2p > MN2) { sc = MAXNORM / sqrtf(x2p); x2 = MN2; }
    float xy  = -(sc * sz) * cz;        // x = -c_source
    float nx  = 1.0f + 2.0f * xy + y2;
    float ny  = 1.0f - x2;
    float inv = 1.0f / fmaxf(1.0f + 2.0f * xy + x2 * y2, 1e-15f);
    float2 zg;
    zg.x = (nx * (-sc * c.x) + ny * (sz * z.x)) * inv;
    zg.y = (nx * (-sc * c.y) + ny * (sz * z.y)) * inv;
    if (p == 0) ((float2*)zbuf)[l] = zg;
  }
  __syncthreads();

  // ---- Stage A: v = Rt @ zg. Wave p owns rows [64p,64p+64), 2 rows/iter.
  // unroll 16 (was 8): ~28 issue-cyc/iter x8 = 224cyc lead vs ~300cyc L2
  // latency -> marginally starved (same diagnosis stage B had; its unroll
  // 8->16 gave -4.2us in r25).
  {
    const float* Rt = rot + (size_t)ct * D_DIM * D_DIM;
    const f32x4 zc = *(const f32x4*)&zbuf[4 * q];
#pragma unroll 16
    for (int t = 0; t < 32; ++t) {
      const int r = 64 * p + 2 * t + h;
      f32x4 rr = *(const f32x4*)&Rt[(size_t)r * D_DIM + 4 * q];
      float pv = fmaf(rr[3], zc[3], fmaf(rr[2], zc[2], fmaf(rr[1], zc[1], rr[0] * zc[0])));
      pv = dpp_sum32(pv);
      if (q == 31) vbuf[r] = pv;
    }
  }
  __syncthreads();

  // ---- Stage B: w_i = sum_j Rs[j][i] v_j. Wave p owns j in [64p,64p+64).
  // unroll 16 (r25-verified win).
  {
    const float* Rs = rot + (size_t)cs * D_DIM * D_DIM;
    f32x4 acc = {0.0f, 0.0f, 0.0f, 0.0f};
#pragma unroll 16
    for (int t = 0; t < 32; ++t) {
      const int j = 64 * p + 2 * t + h;
      f32x4 rr = *(const f32x4*)&Rs[(size_t)j * D_DIM + 4 * q];
      float vj = vbuf[j];
      acc[0] = fmaf(rr[0], vj, acc[0]);
      acc[1] = fmaf(rr[1], vj, acc[1]);
      acc[2] = fmaf(rr[2], vj, acc[2]);
      acc[3] = fmaf(rr[3], vj, acc[3]);
    }
#pragma unroll
    for (int m = 0; m < 4; ++m) acc[m] += __shfl_xor(acc[m], 32, 64);
    if (h == 0) *(f32x4*)&pbuf[p][4 * q] = acc;
  }
  __syncthreads();

  // ---- Mobius B + final projection (replicated in pair; p==0 stores).
  {
    float2 w0 = ((const float2*)pbuf[0])[l];
    float2 w1 = ((const float2*)pbuf[1])[l];
    float2 wv; wv.x = w0.x + w1.x; wv.y = w0.y + w1.y;
    float2 t = ((const float2*)(centers + (size_t)ct * D_DIM))[l];

    float t2p = dpp_sum64(t.x * t.x + t.y * t.y);
    float w2  = dpp_sum64(wv.x * wv.x + wv.y * wv.y);
    float tw  = dpp_sum64(t.x * wv.x + t.y * wv.y);
    float st = 1.0f, x2 = t2p;
    if (t2p > MN2) { st = MAXNORM / sqrtf(t2p); x2 = MN2; }
    float xy  = st * tw;                // x = +c_target
    float nx  = 1.0f + 2.0f * xy + w2;
    float ny  = 1.0f - x2;
    float inv = 1.0f / fmaxf(1.0f + 2.0f * xy + x2 * w2, 1e-15f);
    float o0 = (nx * (st * t.x) + ny * wv.x) * inv;
    float o1 = (nx * (st * t.y) + ny * wv.y) * inv;

    float no2 = dpp_sum64(o0 * o0 + o1 * o1);
    if (no2 > MN2) { float sc = MAXNORM / sqrtf(no2); o0 *= sc; o1 *= sc; }

    if (p == 0) {
      float2 o; o.x = o0; o.y = o1;
      ((float2*)(out + (size_t)b * D_DIM))[l] = o;
    }
  }
}

extern "C" void kernel_launch(void* const* d_in, const int* in_sizes, int n_in,
                              void* d_out, int out_size, void* d_ws, size_t ws_size,
                              hipStream_t stream) {
  const float* z_n     = (const float*)d_in[0];
  const float* centers = (const float*)d_in[1];
  const float* rot     = (const float*)d_in[2];
  const int*   src     = (const int*)d_in[3];
  const int*   tgt     = (const int*)d_in[4];
  float* out = (float*)d_out;
  const int B = in_sizes[3];

  k_all<<<dim3(B), dim3(128), 0, stream>>>(z_n, centers, rot, src, tgt, out, B);
}

// Round 27
// 29.775 us; speedup vs baseline: 1.4738x; 1.4738x over previous
//
#include <hip/hip_runtime.h>
#include <math.h>

#define D_DIM   128
#define MAXNORM 0.99f
#define MN2     (0.99f * 0.99f)

typedef float f32x4 __attribute__((ext_vector_type(4)));

// DPP-based reductions: VALU pipe only (r18-verified).
template <int CTRL, int MASK>
__device__ __forceinline__ float dpp_add(float x) {
  int y = __builtin_amdgcn_update_dpp(0, __float_as_int(x), CTRL, MASK, 0xf, true);
  return x + __int_as_float(y);
}
__device__ __forceinline__ float dpp_sum64(float x) {
  x = dpp_add<0x111, 0xf>(x);   // row_shr:1
  x = dpp_add<0x112, 0xf>(x);   // row_shr:2
  x = dpp_add<0x114, 0xf>(x);   // row_shr:4
  x = dpp_add<0x118, 0xf>(x);   // row_shr:8
  x = dpp_add<0x142, 0xa>(x);   // row_bcast15
  x = dpp_add<0x143, 0xc>(x);   // row_bcast31
  return __int_as_float(__builtin_amdgcn_readlane(__float_as_int(x), 63));
}
__device__ __forceinline__ float dpp_sum32(float x) {
  x = dpp_add<0x111, 0xf>(x);
  x = dpp_add<0x112, 0xf>(x);
  x = dpp_add<0x114, 0xf>(x);
  x = dpp_add<0x118, 0xf>(x);
  x = dpp_add<0x142, 0xa>(x);
  return x;
}

// ONE sample per 128-thread block (2 waves): barriers couple only the waves
// that share data. Unrolls are EXACTLY r25's verified settings (A=8, B=16):
// r26 proved A=16 under the 64-VGPR cap spills (WRITE 48MB scratch traffic).
__global__ __launch_bounds__(128, 8) void k_all(
    const float* __restrict__ z_n, const float* __restrict__ centers,
    const float* __restrict__ rot, const int* __restrict__ src_idx,
    const int* __restrict__ tgt_idx, float* __restrict__ out, int B)
{
  __shared__ float zbuf[D_DIM];      // z_global
  __shared__ float vbuf[D_DIM];      // v = Rt @ zg
  __shared__ float pbuf[2][D_DIM];   // stage-B partials per wave

  const int tid = threadIdx.x;
  const int p = tid >> 6, l = tid & 63;   // wave-in-pair, lane
  const int h = l >> 5, q = l & 31;
  const int b = blockIdx.x;
  if (b >= B) return;

  const int ct = tgt_idx[b];
  const int cs = src_idx[b];

  // ---- Mobius A (replicated in the pair; p==0 publishes). Lane owns comps 2l,2l+1.
  float2 z = ((const float2*)(z_n + (size_t)b * D_DIM))[l];
  float2 c = ((const float2*)(centers + (size_t)cs * D_DIM))[l];
  {
    float y2p = dpp_sum64(z.x * z.x + z.y * z.y);
    float x2p = dpp_sum64(c.x * c.x + c.y * c.y);
    float cz  = dpp_sum64(c.x * z.x + c.y * z.y);
    float sz = 1.0f, y2 = y2p;
    if (y2p > MN2) { sz = MAXNORM / sqrtf(y2p); y2 = MN2; }
    float sc = 1.0f, x2 = x2p;
    if (x2p > MN2) { sc = MAXNORM / sqrtf(x2p); x2 = MN2; }
    float xy  = -(sc * sz) * cz;        // x = -c_source
    float nx  = 1.0f + 2.0f * xy + y2;
    float ny  = 1.0f - x2;
    float inv = 1.0f / fmaxf(1.0f + 2.0f * xy + x2 * y2, 1e-15f);
    float2 zg;
    zg.x = (nx * (-sc * c.x) + ny * (sz * z.x)) * inv;
    zg.y = (nx * (-sc * c.y) + ny * (sz * z.y)) * inv;
    if (p == 0) ((float2*)zbuf)[l] = zg;
  }
  __syncthreads();

  // ---- Stage A: v = Rt @ zg. Wave p owns rows [64p,64p+64), 2 rows/iter.
  // unroll 8 (r25-verified; 16 spills under the 64-VGPR cap -> r26's 48MB scratch).
  {
    const float* Rt = rot + (size_t)ct * D_DIM * D_DIM;
    const f32x4 zc = *(const f32x4*)&zbuf[4 * q];
#pragma unroll 8
    for (int t = 0; t < 32; ++t) {
      const int r = 64 * p + 2 * t + h;
      f32x4 rr = *(const f32x4*)&Rt[(size_t)r * D_DIM + 4 * q];
      float pv = fmaf(rr[3], zc[3], fmaf(rr[2], zc[2], fmaf(rr[1], zc[1], rr[0] * zc[0])));
      pv = dpp_sum32(pv);
      if (q == 31) vbuf[r] = pv;
    }
  }
  __syncthreads();

  // ---- Stage B: w_i = sum_j Rs[j][i] v_j. Wave p owns j in [64p,64p+64).
  // unroll 16 (r25-verified win: latency-starved at 8).
  {
    const float* Rs = rot + (size_t)cs * D_DIM * D_DIM;
    f32x4 acc = {0.0f, 0.0f, 0.0f, 0.0f};
#pragma unroll 16
    for (int t = 0; t < 32; ++t) {
      const int j = 64 * p + 2 * t + h;
      f32x4 rr = *(const f32x4*)&Rs[(size_t)j * D_DIM + 4 * q];
      float vj = vbuf[j];
      acc[0] = fmaf(rr[0], vj, acc[0]);
      acc[1] = fmaf(rr[1], vj, acc[1]);
      acc[2] = fmaf(rr[2], vj, acc[2]);
      acc[3] = fmaf(rr[3], vj, acc[3]);
    }
#pragma unroll
    for (int m = 0; m < 4; ++m) acc[m] += __shfl_xor(acc[m], 32, 64);
    if (h == 0) *(f32x4*)&pbuf[p][4 * q] = acc;
  }
  __syncthreads();

  // ---- Mobius B + final projection (replicated in pair; p==0 stores).
  {
    float2 w0 = ((const float2*)pbuf[0])[l];
    float2 w1 = ((const float2*)pbuf[1])[l];
    float2 wv; wv.x = w0.x + w1.x; wv.y = w0.y + w1.y;
    float2 t = ((const float2*)(centers + (size_t)ct * D_DIM))[l];

    float t2p = dpp_sum64(t.x * t.x + t.y * t.y);
    float w2  = dpp_sum64(wv.x * wv.x + wv.y * wv.y);
    float tw  = dpp_sum64(t.x * wv.x + t.y * wv.y);
    float st = 1.0f, x2 = t2p;
    if (t2p > MN2) { st = MAXNORM / sqrtf(t2p); x2 = MN2; }
    float xy  = st * tw;                // x = +c_target
    float nx  = 1.0f + 2.0f * xy + w2;
    float ny  = 1.0f - x2;
    float inv = 1.0f / fmaxf(1.0f + 2.0f * xy + x2 * w2, 1e-15f);
    float o0 = (nx * (st * t.x) + ny * wv.x) * inv;
    float o1 = (nx * (st * t.y) + ny * wv.y) * inv;

    float no2 = dpp_sum64(o0 * o0 + o1 * o1);
    if (no2 > MN2) { float sc = MAXNORM / sqrtf(no2); o0 *= sc; o1 *= sc; }

    if (p == 0) {
      float2 o; o.x = o0; o.y = o1;
      ((float2*)(out + (size_t)b * D_DIM))[l] = o;
    }
  }
}

extern "C" void kernel_launch(void* const* d_in, const int* in_sizes, int n_in,
                              void* d_out, int out_size, void* d_ws, size_t ws_size,
                              hipStream_t stream) {
  const float* z_n     = (const float*)d_in[0];
  const float* centers = (const float*)d_in[1];
  const float* rot     = (const float*)d_in[2];
  const int*   src     = (const int*)d_in[3];
  const int*   tgt     = (const int*)d_in[4];
  float* out = (float*)d_out;
  const int B = in_sizes[3];

  k_all<<<dim3(B), dim3(128), 0, stream>>>(z_n, centers, rot, src, tgt, out, B);
}